// Round 2
// baseline (152.292 us; speedup 1.0000x reference)
//
#include <hip/hip_runtime.h>
#include <math.h>

// Problem constants (fixed by setup_inputs: B=64, C=1, H=512, W=512 fp32)
static constexpr int Hdim = 512;
static constexpr int Wdim = 512;
static constexpr int HW   = Hdim * Wdim;       // 2^18 px per image
static constexpr int NIMG = 64;
static constexpr int WPR  = Wdim / 64;         // 8 uint64 words per row
static constexpr int RSTRIP = 16;              // rows per block strip (16 -> 2048 blocks, 8/CU)
static constexpr int SPI  = Hdim / RSTRIP;     // strips per image = 32
static constexpr int NBLK = NIMG * SPI;        // 2048 blocks
static constexpr int MROWS = RSTRIP + 4;       // strip rows + /-2 halo = 20
static constexpr int NGRP  = MROWS * (Wdim / 4);   // 2560 4-px nibble groups
static constexpr int GPT   = NGRP / 256;           // 10 groups per thread
static constexpr int NWORDS = MROWS * WPR;         // 160 mask words
static constexpr int NIT = (RSTRIP * Wdim) / (256 * 4);  // 8 phase-3 iters

// d_ws layout: [0, 64KB): per-block partials (NBLK slots x 8 floats, 5 used)
// No zero-init needed: fused kernel overwrites every partial slot each call.

__device__ __forceinline__ unsigned long long shl1(unsigned long long c, unsigned long long l) {
    return (c << 1) | (l >> 63);   // value at x-1
}
__device__ __forceinline__ unsigned long long shr1(unsigned long long c, unsigned long long r) {
    return (c >> 1) | (r << 63);   // value at x+1
}
__device__ __forceinline__ unsigned long long shl2(unsigned long long c, unsigned long long l) {
    return (c << 2) | (l >> 62);
}
__device__ __forceinline__ unsigned long long shr2(unsigned long long c, unsigned long long r) {
    return (c >> 2) | (r << 62);
}

// ---- Fused kernel: target bit-pack (float4) + morphology + elementwise math ----
// __launch_bounds__(256, 8): 8 waves/SIMD -> forces VGPR<=64 so 8 blocks/CU fit.
__global__ __launch_bounds__(256, 8) void fused_loss_kernel(
    const float* __restrict__ inp, const float* __restrict__ tgt,
    float* __restrict__ partials)
{
    // nibw: 2560 nibble-bytes (one per 4-px group), dword-aligned for SWAR pack
    __shared__ unsigned int nibw[NGRP / 4];            // 2560 B
    __shared__ unsigned long long tmask[MROWS][WPR];   // rows r0-2 .. r0+RSTRIP+1
    __shared__ unsigned long long bmask[RSTRIP][WPR];  // boundary bits
    __shared__ float smem[4][5];

    const int img   = blockIdx.x / SPI;
    const int strip = blockIdx.x % SPI;
    const int r0    = strip * RSTRIP;
    const float* ib = inp + img * HW;
    const float* tb = tgt + img * HW;

    const int wave = threadIdx.x >> 6;
    const int lane = threadIdx.x & 63;

    // Early-issue the first half of input float4s: their HBM latency hides
    // under phases 0-2 (they are not consumed until phase 3).
    const float* base = ib + r0 * Wdim + threadIdx.x * 4;
    float4 b0 = *(const float4*)(base + 0 * 1024);
    float4 b1 = *(const float4*)(base + 1 * 1024);
    float4 b2 = *(const float4*)(base + 2 * 1024);
    float4 b3 = *(const float4*)(base + 3 * 1024);

    // ---- Phase 0: targets -> 4-px nibbles in LDS (float4 loads, 16B/lane) ----
    unsigned char* nib = (unsigned char*)nibw;
    #pragma unroll
    for (int i = 0; i < GPT; i++) {
        int g   = threadIdx.x + i * 256;   // group index 0..2559
        int row = g >> 7;                  // 128 groups per row; 0..19
        int c4  = g & 127;
        int gr  = r0 - 2 + row;
        unsigned int n = 0u;
        if ((unsigned)gr < (unsigned)Hdim) {
            float4 v = *(const float4*)(tb + gr * Wdim + c4 * 4);
            n = (unsigned int)(v.x > 0.5f)
              | ((unsigned int)(v.y > 0.5f) << 1)
              | ((unsigned int)(v.z > 0.5f) << 2)
              | ((unsigned int)(v.w > 0.5f) << 3);
        }
        nib[g] = (unsigned char)n;
    }
    __syncthreads();

    // ---- Phase 1: SWAR-pack 16 nibbles -> one 64-bit mask word (160 words) ----
    for (int w = threadIdx.x; w < NWORDS; w += 256) {
        unsigned long long word = 0ULL;
        #pragma unroll
        for (int k = 0; k < 4; k++) {
            unsigned int v = nibw[w * 4 + k];        // 4 nibble-bytes
            unsigned int y = v | (v >> 4);
            unsigned int z = y & 0x00FF00FFu;
            unsigned int h = (z | (z >> 8)) & 0xFFFFu;
            word |= (unsigned long long)h << (16 * k);
        }
        tmask[w >> 3][w & 7] = word;
    }
    __syncthreads();

    // ---- Phase 2: boundary = dilate2 & ~erode2 (radius-2 L1 diamond), bitwise ----
    if (threadIdx.x < RSTRIP * WPR) {      // 128 threads: row 0..15, word 0..7
        int row  = threadIdx.x >> 3;
        int word = threadIdx.x & 7;
        int mr = row + 2;

        #define CW(r)  tmask[r][word]
        #define LW(r)  (word > 0 ? tmask[r][word - 1] : 0ULL)
        #define RW(r)  (word < WPR - 1 ? tmask[r][word + 1] : 0ULL)
        unsigned long long c0 = CW(mr),   l0 = LW(mr),   rr0 = RW(mr);
        unsigned long long cm = CW(mr-1), lm = LW(mr-1), rm  = RW(mr-1);
        unsigned long long cp = CW(mr+1), lp = LW(mr+1), rp  = RW(mr+1);
        unsigned long long cm2 = CW(mr-2);
        unsigned long long cp2 = CW(mr+2);
        #undef CW
        #undef LW
        #undef RW

        unsigned long long er =
            c0 & shl1(c0,l0) & shr1(c0,rr0) & shl2(c0,l0) & shr2(c0,rr0)
               & cm & shl1(cm,lm) & shr1(cm,rm)
               & cp & shl1(cp,lp) & shr1(cp,rp)
               & cm2 & cp2;
        unsigned long long di =
            c0 | shl1(c0,l0) | shr1(c0,rr0) | shl2(c0,l0) | shr2(c0,rr0)
               | cm | shl1(cm,lm) | shr1(cm,rm)
               | cp | shl1(cp,lp) | shr1(cp,rp)
               | cm2 | cp2;
        bmask[row][word] = di & ~er;
    }
    __syncthreads();

    // ---- Phase 3: elementwise math; rolling register pipeline, 2-4 loads in flight ----
    float s_focal = 0.f, s_inter = 0.f, s_p = 0.f, s_bw = 0.f;
    int s_tc = 0;

    auto px4 = [&](int it, float4 v) {
        int flat = it * 1024 + threadIdx.x * 4;   // px within strip
        int row  = flat >> 9;
        int x    = flat & (Wdim - 1);
        unsigned int tb4 = (unsigned int)((tmask[row + 2][x >> 6] >> (x & 63)) & 0xFULL);
        unsigned int bb4 = (unsigned int)((bmask[row][x >> 6]     >> (x & 63)) & 0xFULL);
        s_tc += __popc(tb4);
        const float xs[4] = {v.x, v.y, v.z, v.w};
        #pragma unroll
        for (int k = 0; k < 4; k++) {
            float xi = xs[k];
            bool tpos = (tb4 >> k) & 1;
            float e  = __expf(-fabsf(xi));                  // exp(-|x|)
            float bce = fmaxf(xi, 0.f) - (tpos ? xi : 0.f) + __logf(1.f + e);
            float rden = __builtin_amdgcn_rcpf(1.f + e);
            float p = (xi >= 0.f ? 1.f : e) * rden;         // sigmoid
            float pt = tpos ? p : 1.f - p;                  // == exp(-bce)
            float om = 1.f - pt;
            s_focal += 0.25f * om * om * bce;
            s_p     += p;
            s_inter += tpos ? p : 0.f;
            float wgt = ((bb4 >> k) & 1) ? 6.0f : 1.0f;     // 1 + THETA*boundary
            s_bw += bce * wgt;
        }
    };

    // second half of input loads; keep 2-4 outstanding while computing
    float4 n0 = *(const float4*)(base + 4 * 1024);
    float4 n1 = *(const float4*)(base + 5 * 1024);
    px4(0, b0);
    float4 n2 = *(const float4*)(base + 6 * 1024);
    px4(1, b1);
    float4 n3 = *(const float4*)(base + 7 * 1024);
    px4(2, b2);
    px4(3, b3);
    px4(4, n0);
    px4(5, n1);
    px4(6, n2);
    px4(7, n3);

    float s_t = (float)s_tc;

    // ---- Reduce: wave shuffle -> LDS -> per-block partial store (NO atomics) ----
    #pragma unroll
    for (int off = 32; off > 0; off >>= 1) {
        s_focal += __shfl_down(s_focal, off);
        s_inter += __shfl_down(s_inter, off);
        s_p     += __shfl_down(s_p,     off);
        s_t     += __shfl_down(s_t,     off);
        s_bw    += __shfl_down(s_bw,    off);
    }
    if (lane == 0) {
        smem[wave][0] = s_focal; smem[wave][1] = s_inter; smem[wave][2] = s_p;
        smem[wave][3] = s_t;     smem[wave][4] = s_bw;
    }
    __syncthreads();
    if (threadIdx.x < 5) {
        float a = smem[0][threadIdx.x] + smem[1][threadIdx.x]
                + smem[2][threadIdx.x] + smem[3][threadIdx.x];
        partials[blockIdx.x * 8 + threadIdx.x] = a;
    }
}

// ---- Kernel C: reduce 2048 partial slots, compute final scalar ----
__global__ __launch_bounds__(256) void finalize_kernel(
    const float* __restrict__ partials, float* __restrict__ out)
{
    __shared__ float smem[4][5];
    float a0 = 0.f, a1 = 0.f, a2 = 0.f, a3 = 0.f, a4 = 0.f;
    for (int b = threadIdx.x; b < NBLK; b += 256) {
        const float* s = partials + b * 8;
        a0 += s[0]; a1 += s[1]; a2 += s[2]; a3 += s[3]; a4 += s[4];
    }
    #pragma unroll
    for (int off = 32; off > 0; off >>= 1) {
        a0 += __shfl_down(a0, off);
        a1 += __shfl_down(a1, off);
        a2 += __shfl_down(a2, off);
        a3 += __shfl_down(a3, off);
        a4 += __shfl_down(a4, off);
    }
    int wave = threadIdx.x >> 6;
    int lane = threadIdx.x & 63;
    if (lane == 0) {
        smem[wave][0] = a0; smem[wave][1] = a1; smem[wave][2] = a2;
        smem[wave][3] = a3; smem[wave][4] = a4;
    }
    __syncthreads();
    if (threadIdx.x == 0) {
        double b0 = 0, b1 = 0, b2 = 0, b3 = 0, b4 = 0;
        #pragma unroll
        for (int w = 0; w < 4; w++) {
            b0 += smem[w][0]; b1 += smem[w][1]; b2 += smem[w][2];
            b3 += smem[w][3]; b4 += smem[w][4];
        }
        double invN = 1.0 / (double)(NIMG * HW);
        double focal_loss = b0 * invN;
        double dice = (2.0 * b1 + 1e-6) / (b2 + b3 + 1e-6);
        double boundary_loss = b4 * invN;
        out[0] = (float)(0.3 * focal_loss + 0.4 * (1.0 - dice) + 0.3 * boundary_loss);
    }
}

extern "C" void kernel_launch(void* const* d_in, const int* in_sizes, int n_in,
                              void* d_out, int out_size, void* d_ws, size_t ws_size,
                              hipStream_t stream) {
    const float* inp = (const float*)d_in[0];
    const float* tgt = (const float*)d_in[1];
    float* out = (float*)d_out;
    float* partials = (float*)d_ws;

    fused_loss_kernel<<<NBLK, 256, 0, stream>>>(inp, tgt, partials);
    finalize_kernel<<<1, 256, 0, stream>>>(partials, out);
}

// Round 3
// 151.991 us; speedup vs baseline: 1.0020x; 1.0020x over previous
//
#include <hip/hip_runtime.h>
#include <math.h>

// Problem constants (fixed by setup_inputs: B=64, C=1, H=512, W=512 fp32)
static constexpr int Hdim = 512;
static constexpr int Wdim = 512;
static constexpr int HW   = Hdim * Wdim;       // 2^18 px per image
static constexpr int NIMG = 64;
static constexpr int WPR  = Wdim / 64;         // 8 uint64 words per row
static constexpr int RSTRIP = 16;              // rows per block strip
static constexpr int SPI  = Hdim / RSTRIP;     // strips per image = 32
static constexpr int NBLK = NIMG * SPI;        // 2048 blocks
static constexpr int MROWS = RSTRIP + 4;       // strip rows + /-2 halo = 20
static constexpr int NGRP  = MROWS * (Wdim / 4);   // 2560 4-px nibble groups
static constexpr int GPT   = NGRP / 256;           // 10 target float4 loads per thread
static constexpr int NWORDS = MROWS * WPR;         // 160 mask words
static constexpr int NIT = (RSTRIP * Wdim) / (256 * 4);  // 8 input float4 loads per thread

// d_ws layout: [0, 64KB): per-block partials (NBLK slots x 8 floats, 5 used)
// No zero-init needed: fused kernel overwrites every partial slot each call.

__device__ __forceinline__ unsigned long long shl1(unsigned long long c, unsigned long long l) {
    return (c << 1) | (l >> 63);   // value at x-1
}
__device__ __forceinline__ unsigned long long shr1(unsigned long long c, unsigned long long r) {
    return (c >> 1) | (r << 63);   // value at x+1
}
__device__ __forceinline__ unsigned long long shl2(unsigned long long c, unsigned long long l) {
    return (c << 2) | (l >> 62);
}
__device__ __forceinline__ unsigned long long shr2(unsigned long long c, unsigned long long r) {
    return (c >> 2) | (r << 62);
}

// ---- Fused kernel: burst-load everything, then compute from registers/LDS ----
// __launch_bounds__(256, 4): VGPR cap 128 so ~72 VGPRs of live load data fit.
// Deliberately trading occupancy (R2 showed 60% vs 32% made no difference)
// for per-wave memory-level parallelism (18 loads in flight per thread).
__global__ __launch_bounds__(256, 4) void fused_loss_kernel(
    const float* __restrict__ inp, const float* __restrict__ tgt,
    float* __restrict__ partials)
{
    // nibw: 2560 nibble-bytes (one per 4-px group), dword-aligned for SWAR pack
    __shared__ unsigned int nibw[NGRP / 4];            // 2560 B
    __shared__ unsigned long long tmask[MROWS][WPR];   // rows r0-2 .. r0+RSTRIP+1
    __shared__ unsigned long long bmask[RSTRIP][WPR];  // boundary bits
    __shared__ float smem[4][5];

    const int img   = blockIdx.x / SPI;
    const int strip = blockIdx.x % SPI;
    const int r0    = strip * RSTRIP;
    const float* ib = inp + img * HW;
    const float* tb = tgt + img * HW;

    const int wave = threadIdx.x >> 6;
    const int lane = threadIdx.x & 63;

    // ---- Burst phase: issue ALL loads (10 target + 8 input float4s) ----
    float4 t[GPT];
    #pragma unroll
    for (int i = 0; i < GPT; i++) {
        int g  = threadIdx.x + i * 256;   // group index 0..2559
        int gr = r0 - 2 + (g >> 7);       // 128 groups per row
        t[i] = make_float4(0.f, 0.f, 0.f, 0.f);
        if ((unsigned)gr < (unsigned)Hdim)
            t[i] = *(const float4*)(tb + gr * Wdim + (g & 127) * 4);
    }
    const float* base = ib + r0 * Wdim + threadIdx.x * 4;
    float4 b[NIT];
    #pragma unroll
    for (int it = 0; it < NIT; it++)
        b[it] = *(const float4*)(base + it * 1024);
    // Pin the loads: compiler may not sink a global load past a memory clobber,
    // so all 18 stay issued here with progressive vmcnt drains at first use.
    asm volatile("" ::: "memory");

    // ---- Phase 0: targets -> 4-px nibbles in LDS ----
    unsigned char* nib = (unsigned char*)nibw;
    #pragma unroll
    for (int i = 0; i < GPT; i++) {
        int g = threadIdx.x + i * 256;
        unsigned int n = (unsigned int)(t[i].x > 0.5f)
                       | ((unsigned int)(t[i].y > 0.5f) << 1)
                       | ((unsigned int)(t[i].z > 0.5f) << 2)
                       | ((unsigned int)(t[i].w > 0.5f) << 3);
        nib[g] = (unsigned char)n;
    }
    __syncthreads();

    // ---- Phase 1: SWAR-pack 16 nibbles -> one 64-bit mask word (160 words) ----
    for (int w = threadIdx.x; w < NWORDS; w += 256) {
        unsigned long long word = 0ULL;
        #pragma unroll
        for (int k = 0; k < 4; k++) {
            unsigned int v = nibw[w * 4 + k];        // 4 nibble-bytes
            unsigned int y = v | (v >> 4);
            unsigned int z = y & 0x00FF00FFu;
            unsigned int h = (z | (z >> 8)) & 0xFFFFu;
            word |= (unsigned long long)h << (16 * k);
        }
        tmask[w >> 3][w & 7] = word;
    }
    __syncthreads();

    // ---- Phase 2: boundary = dilate2 & ~erode2 (radius-2 L1 diamond), bitwise ----
    if (threadIdx.x < RSTRIP * WPR) {      // 128 threads: row 0..15, word 0..7
        int row  = threadIdx.x >> 3;
        int word = threadIdx.x & 7;
        int mr = row + 2;

        #define CW(r)  tmask[r][word]
        #define LW(r)  (word > 0 ? tmask[r][word - 1] : 0ULL)
        #define RW(r)  (word < WPR - 1 ? tmask[r][word + 1] : 0ULL)
        unsigned long long c0 = CW(mr),   l0 = LW(mr),   rr0 = RW(mr);
        unsigned long long cm = CW(mr-1), lm = LW(mr-1), rm  = RW(mr-1);
        unsigned long long cp = CW(mr+1), lp = LW(mr+1), rp  = RW(mr+1);
        unsigned long long cm2 = CW(mr-2);
        unsigned long long cp2 = CW(mr+2);
        #undef CW
        #undef LW
        #undef RW

        unsigned long long er =
            c0 & shl1(c0,l0) & shr1(c0,rr0) & shl2(c0,l0) & shr2(c0,rr0)
               & cm & shl1(cm,lm) & shr1(cm,rm)
               & cp & shl1(cp,lp) & shr1(cp,rp)
               & cm2 & cp2;
        unsigned long long di =
            c0 | shl1(c0,l0) | shr1(c0,rr0) | shl2(c0,l0) | shr2(c0,rr0)
               | cm | shl1(cm,lm) | shr1(cm,rm)
               | cp | shl1(cp,lp) | shr1(cp,rp)
               | cm2 | cp2;
        bmask[row][word] = di & ~er;
    }
    __syncthreads();

    // ---- Phase 3: elementwise math, fully from registers + LDS masks ----
    float s_focal = 0.f, s_inter = 0.f, s_p = 0.f, s_bw = 0.f;
    int s_tc = 0;

    #pragma unroll
    for (int it = 0; it < NIT; it++) {
        float4 v = b[it];
        int flat = it * 1024 + threadIdx.x * 4;   // px within strip
        int row  = flat >> 9;
        int x    = flat & (Wdim - 1);
        unsigned int tb4 = (unsigned int)((tmask[row + 2][x >> 6] >> (x & 63)) & 0xFULL);
        unsigned int bb4 = (unsigned int)((bmask[row][x >> 6]     >> (x & 63)) & 0xFULL);
        s_tc += __popc(tb4);
        const float xs[4] = {v.x, v.y, v.z, v.w};
        #pragma unroll
        for (int k = 0; k < 4; k++) {
            float xi = xs[k];
            bool tpos = (tb4 >> k) & 1;
            float e  = __expf(-fabsf(xi));                  // exp(-|x|)
            float bce = fmaxf(xi, 0.f) - (tpos ? xi : 0.f) + __logf(1.f + e);
            float rden = __builtin_amdgcn_rcpf(1.f + e);
            float p = (xi >= 0.f ? 1.f : e) * rden;         // sigmoid
            float pt = tpos ? p : 1.f - p;                  // == exp(-bce)
            float om = 1.f - pt;
            s_focal += 0.25f * om * om * bce;
            s_p     += p;
            s_inter += tpos ? p : 0.f;
            float wgt = ((bb4 >> k) & 1) ? 6.0f : 1.0f;     // 1 + THETA*boundary
            s_bw += bce * wgt;
        }
    }
    float s_t = (float)s_tc;

    // ---- Reduce: wave shuffle -> LDS -> per-block partial store (NO atomics) ----
    #pragma unroll
    for (int off = 32; off > 0; off >>= 1) {
        s_focal += __shfl_down(s_focal, off);
        s_inter += __shfl_down(s_inter, off);
        s_p     += __shfl_down(s_p,     off);
        s_t     += __shfl_down(s_t,     off);
        s_bw    += __shfl_down(s_bw,    off);
    }
    if (lane == 0) {
        smem[wave][0] = s_focal; smem[wave][1] = s_inter; smem[wave][2] = s_p;
        smem[wave][3] = s_t;     smem[wave][4] = s_bw;
    }
    __syncthreads();
    if (threadIdx.x < 5) {
        float a = smem[0][threadIdx.x] + smem[1][threadIdx.x]
                + smem[2][threadIdx.x] + smem[3][threadIdx.x];
        partials[blockIdx.x * 8 + threadIdx.x] = a;
    }
}

// ---- Kernel C: reduce 2048 partial slots, compute final scalar ----
__global__ __launch_bounds__(256) void finalize_kernel(
    const float* __restrict__ partials, float* __restrict__ out)
{
    __shared__ float smem[4][5];
    float a0 = 0.f, a1 = 0.f, a2 = 0.f, a3 = 0.f, a4 = 0.f;
    for (int b = threadIdx.x; b < NBLK; b += 256) {
        const float* s = partials + b * 8;
        a0 += s[0]; a1 += s[1]; a2 += s[2]; a3 += s[3]; a4 += s[4];
    }
    #pragma unroll
    for (int off = 32; off > 0; off >>= 1) {
        a0 += __shfl_down(a0, off);
        a1 += __shfl_down(a1, off);
        a2 += __shfl_down(a2, off);
        a3 += __shfl_down(a3, off);
        a4 += __shfl_down(a4, off);
    }
    int wave = threadIdx.x >> 6;
    int lane = threadIdx.x & 63;
    if (lane == 0) {
        smem[wave][0] = a0; smem[wave][1] = a1; smem[wave][2] = a2;
        smem[wave][3] = a3; smem[wave][4] = a4;
    }
    __syncthreads();
    if (threadIdx.x == 0) {
        double b0 = 0, b1 = 0, b2 = 0, b3 = 0, b4 = 0;
        #pragma unroll
        for (int w = 0; w < 4; w++) {
            b0 += smem[w][0]; b1 += smem[w][1]; b2 += smem[w][2];
            b3 += smem[w][3]; b4 += smem[w][4];
        }
        double invN = 1.0 / (double)(NIMG * HW);
        double focal_loss = b0 * invN;
        double dice = (2.0 * b1 + 1e-6) / (b2 + b3 + 1e-6);
        double boundary_loss = b4 * invN;
        out[0] = (float)(0.3 * focal_loss + 0.4 * (1.0 - dice) + 0.3 * boundary_loss);
    }
}

extern "C" void kernel_launch(void* const* d_in, const int* in_sizes, int n_in,
                              void* d_out, int out_size, void* d_ws, size_t ws_size,
                              hipStream_t stream) {
    const float* inp = (const float*)d_in[0];
    const float* tgt = (const float*)d_in[1];
    float* out = (float*)d_out;
    float* partials = (float*)d_ws;

    fused_loss_kernel<<<NBLK, 256, 0, stream>>>(inp, tgt, partials);
    finalize_kernel<<<1, 256, 0, stream>>>(partials, out);
}

// Round 5
// 144.931 us; speedup vs baseline: 1.0508x; 1.0487x over previous
//
#include <hip/hip_runtime.h>
#include <math.h>

// Problem constants (fixed by setup_inputs: B=64, C=1, H=512, W=512 fp32)
static constexpr int Hdim = 512;
static constexpr int Wdim = 512;
static constexpr int HW   = Hdim * Wdim;       // 2^18 px per image
static constexpr int NIMG = 64;
static constexpr int WPR  = Wdim / 64;         // 8 uint64 words per row
static constexpr int RSTRIP = 16;              // rows per block strip
static constexpr int SPI  = Hdim / RSTRIP;     // strips per image = 32
static constexpr int NBLK = NIMG * SPI;        // 2048 blocks
static constexpr int MROWS = RSTRIP + 4;       // strip rows + /-2 halo = 20
static constexpr int NGRP  = MROWS * (Wdim / 4);   // 2560 4-px nibble groups
static constexpr int GPT   = NGRP / 256;           // 10 target float4 loads per thread
static constexpr int NWORDS = MROWS * WPR;         // 160 mask words
static constexpr int NIT = (RSTRIP * Wdim) / (256 * 4);  // 8 input float4 loads per thread

// Native clang vector type: __builtin_nontemporal_load accepts this
// (HIP's float4 is a struct and is rejected).
typedef float f32x4 __attribute__((ext_vector_type(4)));

// d_ws layout: [0, 64KB): per-block partials (NBLK slots x 8 floats, 5 used)
// No zero-init needed: fused kernel overwrites every partial slot each call.

__device__ __forceinline__ unsigned long long shl1(unsigned long long c, unsigned long long l) {
    return (c << 1) | (l >> 63);   // value at x-1
}
__device__ __forceinline__ unsigned long long shr1(unsigned long long c, unsigned long long r) {
    return (c >> 1) | (r << 63);   // value at x+1
}
__device__ __forceinline__ unsigned long long shl2(unsigned long long c, unsigned long long l) {
    return (c << 2) | (l >> 62);
}
__device__ __forceinline__ unsigned long long shr2(unsigned long long c, unsigned long long r) {
    return (c >> 2) | (r << 62);
}

// ---- Fused kernel: burst nontemporal loads, then compute from registers/LDS ----
// R1-R3 established: occupancy (32->60%) and per-wave MLP (1->18) do NOT move
// the ~2.9 TB/s read wall. This round tests the cache-path theory: nt loads
// stream past L2/L3 allocation (inputs have zero reuse; poison fill trashes
// L3 between iterations anyway).
__global__ __launch_bounds__(256) void fused_loss_kernel(
    const float* __restrict__ inp, const float* __restrict__ tgt,
    float* __restrict__ partials)
{
    // nibw: 2560 nibble-bytes (one per 4-px group), dword-aligned for SWAR pack
    __shared__ unsigned int nibw[NGRP / 4];            // 2560 B
    __shared__ unsigned long long tmask[MROWS][WPR];   // rows r0-2 .. r0+RSTRIP+1
    __shared__ unsigned long long bmask[RSTRIP][WPR];  // boundary bits
    __shared__ float smem[4][5];

    const int img   = blockIdx.x / SPI;
    const int strip = blockIdx.x % SPI;
    const int r0    = strip * RSTRIP;
    const float* ib = inp + img * HW;
    const float* tb = tgt + img * HW;

    const int wave = threadIdx.x >> 6;
    const int lane = threadIdx.x & 63;

    // ---- Burst phase: issue ALL loads (10 target + 8 input float4s), nt policy ----
    f32x4 t[GPT];
    #pragma unroll
    for (int i = 0; i < GPT; i++) {
        int g  = threadIdx.x + i * 256;   // group index 0..2559
        int gr = r0 - 2 + (g >> 7);       // 128 groups per row
        t[i] = (f32x4){0.f, 0.f, 0.f, 0.f};
        if ((unsigned)gr < (unsigned)Hdim)
            t[i] = __builtin_nontemporal_load((const f32x4*)(tb + gr * Wdim + (g & 127) * 4));
    }
    const float* base = ib + r0 * Wdim + threadIdx.x * 4;
    f32x4 b[NIT];
    #pragma unroll
    for (int it = 0; it < NIT; it++)
        b[it] = __builtin_nontemporal_load((const f32x4*)(base + it * 1024));
    asm volatile("" ::: "memory");

    // ---- Phase 0: targets -> 4-px nibbles in LDS ----
    unsigned char* nib = (unsigned char*)nibw;
    #pragma unroll
    for (int i = 0; i < GPT; i++) {
        int g = threadIdx.x + i * 256;
        unsigned int n = (unsigned int)(t[i].x > 0.5f)
                       | ((unsigned int)(t[i].y > 0.5f) << 1)
                       | ((unsigned int)(t[i].z > 0.5f) << 2)
                       | ((unsigned int)(t[i].w > 0.5f) << 3);
        nib[g] = (unsigned char)n;
    }
    __syncthreads();

    // ---- Phase 1: SWAR-pack 16 nibbles -> one 64-bit mask word (160 words) ----
    for (int w = threadIdx.x; w < NWORDS; w += 256) {
        unsigned long long word = 0ULL;
        #pragma unroll
        for (int k = 0; k < 4; k++) {
            unsigned int v = nibw[w * 4 + k];        // 4 nibble-bytes
            unsigned int y = v | (v >> 4);
            unsigned int z = y & 0x00FF00FFu;
            unsigned int h = (z | (z >> 8)) & 0xFFFFu;
            word |= (unsigned long long)h << (16 * k);
        }
        tmask[w >> 3][w & 7] = word;
    }
    __syncthreads();

    // ---- Phase 2: boundary = dilate2 & ~erode2 (radius-2 L1 diamond), bitwise ----
    if (threadIdx.x < RSTRIP * WPR) {      // 128 threads: row 0..15, word 0..7
        int row  = threadIdx.x >> 3;
        int word = threadIdx.x & 7;
        int mr = row + 2;

        #define CW(r)  tmask[r][word]
        #define LW(r)  (word > 0 ? tmask[r][word - 1] : 0ULL)
        #define RW(r)  (word < WPR - 1 ? tmask[r][word + 1] : 0ULL)
        unsigned long long c0 = CW(mr),   l0 = LW(mr),   rr0 = RW(mr);
        unsigned long long cm = CW(mr-1), lm = LW(mr-1), rm  = RW(mr-1);
        unsigned long long cp = CW(mr+1), lp = LW(mr+1), rp  = RW(mr+1);
        unsigned long long cm2 = CW(mr-2);
        unsigned long long cp2 = CW(mr+2);
        #undef CW
        #undef LW
        #undef RW

        unsigned long long er =
            c0 & shl1(c0,l0) & shr1(c0,rr0) & shl2(c0,l0) & shr2(c0,rr0)
               & cm & shl1(cm,lm) & shr1(cm,rm)
               & cp & shl1(cp,lp) & shr1(cp,rp)
               & cm2 & cp2;
        unsigned long long di =
            c0 | shl1(c0,l0) | shr1(c0,rr0) | shl2(c0,l0) | shr2(c0,rr0)
               | cm | shl1(cm,lm) | shr1(cm,rm)
               | cp | shl1(cp,lp) | shr1(cp,rp)
               | cm2 | cp2;
        bmask[row][word] = di & ~er;
    }
    __syncthreads();

    // ---- Phase 3: elementwise math, fully from registers + LDS masks ----
    float s_focal = 0.f, s_inter = 0.f, s_p = 0.f, s_bw = 0.f;
    int s_tc = 0;

    #pragma unroll
    for (int it = 0; it < NIT; it++) {
        f32x4 v = b[it];
        int flat = it * 1024 + threadIdx.x * 4;   // px within strip
        int row  = flat >> 9;
        int x    = flat & (Wdim - 1);
        unsigned int tb4 = (unsigned int)((tmask[row + 2][x >> 6] >> (x & 63)) & 0xFULL);
        unsigned int bb4 = (unsigned int)((bmask[row][x >> 6]     >> (x & 63)) & 0xFULL);
        s_tc += __popc(tb4);
        const float xs[4] = {v.x, v.y, v.z, v.w};
        #pragma unroll
        for (int k = 0; k < 4; k++) {
            float xi = xs[k];
            bool tpos = (tb4 >> k) & 1;
            float e  = __expf(-fabsf(xi));                  // exp(-|x|)
            float bce = fmaxf(xi, 0.f) - (tpos ? xi : 0.f) + __logf(1.f + e);
            float rden = __builtin_amdgcn_rcpf(1.f + e);
            float p = (xi >= 0.f ? 1.f : e) * rden;         // sigmoid
            float pt = tpos ? p : 1.f - p;                  // == exp(-bce)
            float om = 1.f - pt;
            s_focal += 0.25f * om * om * bce;
            s_p     += p;
            s_inter += tpos ? p : 0.f;
            float wgt = ((bb4 >> k) & 1) ? 6.0f : 1.0f;     // 1 + THETA*boundary
            s_bw += bce * wgt;
        }
    }
    float s_t = (float)s_tc;

    // ---- Reduce: wave shuffle -> LDS -> per-block partial store (NO atomics) ----
    #pragma unroll
    for (int off = 32; off > 0; off >>= 1) {
        s_focal += __shfl_down(s_focal, off);
        s_inter += __shfl_down(s_inter, off);
        s_p     += __shfl_down(s_p,     off);
        s_t     += __shfl_down(s_t,     off);
        s_bw    += __shfl_down(s_bw,    off);
    }
    if (lane == 0) {
        smem[wave][0] = s_focal; smem[wave][1] = s_inter; smem[wave][2] = s_p;
        smem[wave][3] = s_t;     smem[wave][4] = s_bw;
    }
    __syncthreads();
    if (threadIdx.x < 5) {
        float a = smem[0][threadIdx.x] + smem[1][threadIdx.x]
                + smem[2][threadIdx.x] + smem[3][threadIdx.x];
        partials[blockIdx.x * 8 + threadIdx.x] = a;
    }
}

// ---- Kernel C: reduce 2048 partial slots, compute final scalar ----
__global__ __launch_bounds__(256) void finalize_kernel(
    const float* __restrict__ partials, float* __restrict__ out)
{
    __shared__ float smem[4][5];
    float a0 = 0.f, a1 = 0.f, a2 = 0.f, a3 = 0.f, a4 = 0.f;
    for (int b = threadIdx.x; b < NBLK; b += 256) {
        const float* s = partials + b * 8;
        a0 += s[0]; a1 += s[1]; a2 += s[2]; a3 += s[3]; a4 += s[4];
    }
    #pragma unroll
    for (int off = 32; off > 0; off >>= 1) {
        a0 += __shfl_down(a0, off);
        a1 += __shfl_down(a1, off);
        a2 += __shfl_down(a2, off);
        a3 += __shfl_down(a3, off);
        a4 += __shfl_down(a4, off);
    }
    int wave = threadIdx.x >> 6;
    int lane = threadIdx.x & 63;
    if (lane == 0) {
        smem[wave][0] = a0; smem[wave][1] = a1; smem[wave][2] = a2;
        smem[wave][3] = a3; smem[wave][4] = a4;
    }
    __syncthreads();
    if (threadIdx.x == 0) {
        double b0 = 0, b1 = 0, b2 = 0, b3 = 0, b4 = 0;
        #pragma unroll
        for (int w = 0; w < 4; w++) {
            b0 += smem[w][0]; b1 += smem[w][1]; b2 += smem[w][2];
            b3 += smem[w][3]; b4 += smem[w][4];
        }
        double invN = 1.0 / (double)(NIMG * HW);
        double focal_loss = b0 * invN;
        double dice = (2.0 * b1 + 1e-6) / (b2 + b3 + 1e-6);
        double boundary_loss = b4 * invN;
        out[0] = (float)(0.3 * focal_loss + 0.4 * (1.0 - dice) + 0.3 * boundary_loss);
    }
}

extern "C" void kernel_launch(void* const* d_in, const int* in_sizes, int n_in,
                              void* d_out, int out_size, void* d_ws, size_t ws_size,
                              hipStream_t stream) {
    const float* inp = (const float*)d_in[0];
    const float* tgt = (const float*)d_in[1];
    float* out = (float*)d_out;
    float* partials = (float*)d_ws;

    fused_loss_kernel<<<NBLK, 256, 0, stream>>>(inp, tgt, partials);
    finalize_kernel<<<1, 256, 0, stream>>>(partials, out);
}